// Round 13
// baseline (404.156 us; speedup 1.0000x reference)
//
#include <hip/hip_runtime.h>
#include <stdint.h>

// Problem dims (fixed by reference)
#define M_ROWS 8192
#define K_DIM  4096
#define OUTD   144     // per-branch flat size (78 real + 66 imag)
#define PLANE  1179648 // complex elements per output plane (8192*144), u32 units
#define KCH    8       // split-K chunks
#define NSTEP  8       // (K_DIM/KCH)/64 steps of 64k per chunk

typedef __attribute__((ext_vector_type(4))) float  float4v;
typedef __attribute__((ext_vector_type(8))) short  short8v;

static __device__ __forceinline__ unsigned short f2bf(float f) {
    // round-to-nearest-even fp32 -> bf16
    unsigned int u = __builtin_bit_cast(unsigned int, f);
    u += 0x7FFFu + ((u >> 16) & 1u);
    return (unsigned short)(u >> 16);
}

// ---------------------------------------------------------------------------
// Prep: Wt2 frag-major layout (unchanged, verified rounds 8-12).
// ---------------------------------------------------------------------------
__global__ __launch_bounds__(256) void wt_kernel(
    const float* __restrict__ WC1, const float* __restrict__ WR1,
    unsigned short* __restrict__ Wt) {
    __shared__ float tile[64][65];
    const float* src = (blockIdx.y == 0) ? WC1 : WR1;
    const int k0 = blockIdx.x * 64;
    const int t = threadIdx.x;
    const int j = t & 63, qq = t >> 6;
#pragma unroll
    for (int p = 0; p < 16; ++p) {
        int i = p * 4 + qq;
        tile[i][j] = src[(size_t)(k0 + i) * 64 + j];   // tile[k'][n']
    }
    __syncthreads();
    const int tt  = blockIdx.x >> 1;        // k-tile (128-wide)
    const int ksb = (blockIdx.x & 1) * 2;   // ks base within tile
#pragma unroll
    for (int p = 0; p < 16; ++p) {
        int c = p * 256 + t;
        int e = c & 7, m = (c >> 3) & 15, q = (c >> 7) & 3;
        int ks_l = (c >> 9) & 1, w_l = (c >> 10) & 3;
        int kp = ks_l * 32 + q * 8 + e;               // k within 64-block
        int np = w_l * 16 + m;                        // n within 64-block
        int wg = blockIdx.y * 4 + w_l;                // global wave-col group
        size_t dst = ((size_t)(wg * 32 + tt) * 4 + (ksb + ks_l)) * 512
                   + q * 128 + m * 8 + e;
        Wt[dst] = f2bf(tile[kp][np]);
    }
}

// ---------------------------------------------------------------------------
// Round 13: MEASUREMENT ROUND. Code byte-identical to round 12; the launcher
// runs gemm1 FIVE times (idempotent: pure X,Wt -> PART). The dur_us delta vs
// round 12 (273.1) gives g_warm = (dur13 - 273.1)/4 — the first direct
// observation of the gemm1/tail split, which the top-5 fill rows have masked.
// ---------------------------------------------------------------------------

#define ISSUE_AX(S_, X0_, X1_, X2_, X3_)                       \
    do { const float* ap_ = xpw + (S_) * 64;                   \
         X0_ = *(const float4*)(ap_);                          \
         X1_ = *(const float4*)(ap_ + 4);                      \
         X2_ = *(const float4*)(ap_ + 32);                     \
         X3_ = *(const float4*)(ap_ + 36); } while (0)

#define STORE_AX(BUF_, X0_, X1_, X2_, X3_)                             \
    do { short8v s1_, s2_;                                             \
         s1_[0] = (short)f2bf((X0_).x); s1_[1] = (short)f2bf((X0_).y); \
         s1_[2] = (short)f2bf((X0_).z); s1_[3] = (short)f2bf((X0_).w); \
         s1_[4] = (short)f2bf((X1_).x); s1_[5] = (short)f2bf((X1_).y); \
         s1_[6] = (short)f2bf((X1_).z); s1_[7] = (short)f2bf((X1_).w); \
         s2_[0] = (short)f2bf((X2_).x); s2_[1] = (short)f2bf((X2_).y); \
         s2_[2] = (short)f2bf((X2_).z); s2_[3] = (short)f2bf((X2_).w); \
         s2_[4] = (short)f2bf((X3_).x); s2_[5] = (short)f2bf((X3_).y); \
         s2_[6] = (short)f2bf((X3_).z); s2_[7] = (short)f2bf((X3_).w); \
         *(short8v*)(awp + (BUF_) * 8192) = s1_;                       \
         *(short8v*)(awp + (BUF_) * 8192 + 512) = s2_; } while (0)

#define ISSUE_B2(S_, B0_, B1_)                                   \
    do { const unsigned short* bp_ = bpw + (size_t)(2 * (S_)) * 512; \
         B0_ = *(const short8v*)(bp_);                           \
         B1_ = *(const short8v*)(bp_ + 512); } while (0)

#define MFR2(BUF_, B0_, B1_)                                                   \
    do { _Pragma("unroll")                                                     \
         for (int rb = 0; rb < 8; ++rb) {                                      \
             const unsigned short* ab_ = Asm_ + (BUF_) * 8192 + rb * 1024 + lane * 8; \
             short8v a0_ = *(const short8v*)(ab_);                             \
             short8v a1_ = *(const short8v*)(ab_ + 512);                       \
             acc[rb] = __builtin_amdgcn_mfma_f32_16x16x32_bf16(a0_, B0_, acc[rb], 0, 0, 0); \
             acc[rb] = __builtin_amdgcn_mfma_f32_16x16x32_bf16(a1_, B1_, acc[rb], 0, 0, 0); \
         } } while (0)

__global__ __launch_bounds__(512, 4) void gemm1_kernel(
    const float* __restrict__ X, const unsigned short* __restrict__ Wt,
    float* __restrict__ PART) {
    __shared__ __align__(16) unsigned short Asm_[2 * 8192];

    const int tid  = threadIdx.x;
    const int lane = tid & 63;
    const int w    = tid >> 6;          // wave -> col tile [16w,16w+16)
    const int m    = lane & 15, q = lane >> 4;
    const int mt   = blockIdx.x & 63;   // M-tile (128 rows)
    const int kc   = blockIdx.x >> 6;   // K-chunk (512 k)
    const int r0   = mt * 128;

    const int srow = tid & 127, sq8 = tid >> 7;
    const float* xpw = X + (size_t)(r0 + srow) * K_DIM + kc * 512 + sq8 * 8;
    unsigned short* awp = Asm_ + (srow >> 4) * 1024 + (16 * sq8 + (srow & 15)) * 8;

    const unsigned short* bpw = Wt + (size_t)(w * 128 + kc * 16) * 512 + lane * 8;

    float4v acc[8];
#pragma unroll
    for (int rb = 0; rb < 8; ++rb) acc[rb] = (float4v){0.f, 0.f, 0.f, 0.f};

    float4 xa0, xa1, xa2, xa3;
    short8v bA0, bA1, bB0, bB1;

    ISSUE_AX(0, xa0, xa1, xa2, xa3);
    ISSUE_B2(0, bA0, bA1);

#pragma unroll 1
    for (int sp = 0; sp < NSTEP / 2; ++sp) {
        const int s = sp * 2;
        STORE_AX(0, xa0, xa1, xa2, xa3);
        ISSUE_AX(s + 1, xa0, xa1, xa2, xa3);
        asm volatile("s_waitcnt lgkmcnt(0)" ::: "memory");
        __builtin_amdgcn_s_barrier();
        __builtin_amdgcn_sched_barrier(0);
        ISSUE_B2(s + 1, bB0, bB1);
        MFR2(0, bA0, bA1);
        STORE_AX(1, xa0, xa1, xa2, xa3);
        if (s + 2 < NSTEP) ISSUE_AX(s + 2, xa0, xa1, xa2, xa3);
        asm volatile("s_waitcnt lgkmcnt(0)" ::: "memory");
        __builtin_amdgcn_s_barrier();
        __builtin_amdgcn_sched_barrier(0);
        if (s + 2 < NSTEP) ISSUE_B2(s + 2, bA0, bA1);
        MFR2(1, bB0, bB1);
    }

    {
        float* Pf = PART + (size_t)kc * (M_ROWS * 128);
        const int col = w * 16 + m;
#pragma unroll
        for (int rb = 0; rb < 8; ++rb)
#pragma unroll
            for (int i = 0; i < 4; ++i) {
                int grow = r0 + rb * 16 + q * 4 + i;
                Pf[(size_t)grow * 128 + col] = acc[rb][i];
            }
    }
}

// ---------------- tail: reduce partials -> h1, then phases 2-5 -------------
__global__ __launch_bounds__(512, 6) void tail_kernel(
    const float* __restrict__ PART,
    const float* __restrict__ bC1, const float* __restrict__ bR1,
    const float* __restrict__ WC2, const float* __restrict__ bC2,
    const float* __restrict__ WR2, const float* __restrict__ bR2,
    const float* __restrict__ WC3, const float* __restrict__ bC3,
    const float* __restrict__ WR3, const float* __restrict__ bR3,
    unsigned int* __restrict__ O32) {
    __shared__ __align__(16) char smem[41216];
    float* hs  = (float*)smem;                             // [16][132]
    float* W2s = hs + 16 * 132;                            // [64][128]
    float* fl  = W2s;                                      // [16][288]

    const int tid = threadIdx.x;
    const int r0  = blockIdx.x * 16;

    // Reduce 8 K-chunk partials -> h1 = relu(sum + b1) -> hs
    {
        int r = tid >> 5, c4 = tid & 31;
        const float* p0 = PART + (size_t)(r0 + r) * 128 + c4 * 4;
        float4 s = *(const float4*)(p0);
#pragma unroll
        for (int kc = 1; kc < KCH; ++kc) {
            float4 v = *(const float4*)(p0 + (size_t)kc * (M_ROWS * 128));
            s.x += v.x; s.y += v.y; s.z += v.z; s.w += v.w;
        }
        int c = c4 * 4;
        const float* bsrc = (c < 64) ? (bC1 + c) : (bR1 + (c - 64));
        s.x += bsrc[0]; s.y += bsrc[1]; s.z += bsrc[2]; s.w += bsrc[3];
        s.x = s.x > 0.f ? s.x : 0.f;  s.y = s.y > 0.f ? s.y : 0.f;
        s.z = s.z > 0.f ? s.z : 0.f;  s.w = s.w > 0.f ? s.w : 0.f;
        *(float4*)&hs[r * 132 + c] = s;
    }
#pragma unroll
    for (int p = 0; p < 4; ++p) {
        int fi = p * 512 + tid;
        int k = fi >> 5, c4 = fi & 31;
        int c = c4 * 4;
        const float* wsrc = (c < 64) ? (WC2 + (size_t)k * 64 + c)
                                     : (WR2 + (size_t)k * 64 + (c - 64));
        *(float4*)&W2s[k * 128 + c] = *(const float4*)wsrc;
    }
    __syncthreads();

    // Phase 2: layer 2
    const int rg = tid >> 5;
    const int cg = tid & 31;
    const int koff2 = (cg < 16) ? 0 : 64;
    float acc2[4];
    {
        int c = cg * 4;
        const float* bsrc = (c < 64) ? (bC2 + c) : (bR2 + (c - 64));
#pragma unroll
        for (int j = 0; j < 4; ++j) acc2[j] = bsrc[j];
    }
    for (int k = 0; k < 64; ++k) {
        float4 wv = *(const float4*)&W2s[k * 128 + cg * 4];
        float a = hs[rg * 132 + koff2 + k];
        acc2[0] += a * wv.x; acc2[1] += a * wv.y;
        acc2[2] += a * wv.z; acc2[3] += a * wv.w;
    }
    float4 h2v;
    h2v.x = acc2[0] > 0.f ? acc2[0] : 0.f;
    h2v.y = acc2[1] > 0.f ? acc2[1] : 0.f;
    h2v.z = acc2[2] > 0.f ? acc2[2] : 0.f;
    h2v.w = acc2[3] > 0.f ? acc2[3] : 0.f;
    __syncthreads();
    *(float4*)&hs[rg * 132 + cg * 4] = h2v;   // hs now holds h2
    __syncthreads();

    // Phase 3: layer 3 -> fl[16][288]
#pragma unroll 1
    for (int pass = 0; pass < 3; ++pass) {
        int c = pass * 128 + cg * 4;
        if (c < 288) {
            const int brn = (c >= 144);
            const int cl = c - (brn ? 144 : 0);
            const float* W3 = brn ? WR3 : WC3;
            const float* b3 = brn ? bR3 : bC3;
            const int ko = brn ? 64 : 0;
            float a3[4];
#pragma unroll
            for (int j = 0; j < 4; ++j) a3[j] = b3[cl + j];
            for (int k = 0; k < 64; ++k) {
                float4 wv = *(const float4*)(W3 + (size_t)k * OUTD + cl);
                float a = hs[rg * 132 + ko + k];
                a3[0] += a * wv.x; a3[1] += a * wv.y;
                a3[2] += a * wv.z; a3[3] += a * wv.w;
            }
            float4 v; v.x = a3[0]; v.y = a3[1]; v.z = a3[2]; v.w = a3[3];
            *(float4*)&fl[rg * 288 + c] = v;
        }
    }
    __syncthreads();

    // Phase 4: softplus on diag reals
    if (tid < 384) {
        int r = tid / 24, rem = tid % 24;
        int brn = rem / 12, ii = rem % 12;
        float* f = &fl[r * 288 + brn * 144];
        int d = ii * (ii + 1) / 2 + ii;
        float xv = f[d];
        f[d] = (xv > 20.f) ? xv : log1pf(expf(xv));
    }
    __syncthreads();

    // Phase 5: C = L L^H, Hermitian mirror, write OUT
    for (int task = tid; task < 16 * 2 * 78; task += 512) {
        int r = task / 156, rem = task % 156;
        int brn = rem / 78, p = rem % 78;
        int i = 0;
        while (p >= (i + 1) * (i + 2) / 2) ++i;
        int j = p - i * (i + 1) / 2;              // j <= i
        const float* f = &fl[r * 288 + brn * 144];
        const float* g = f + 78;
        const int ti = i * (i + 1) / 2, tj = j * (j + 1) / 2;
        const int si = i * (i - 1) / 2, sj = j * (j - 1) / 2;
        float re = 0.f, im = 0.f;
        for (int k = 0; k <= j; ++k) {
            float ar_ = f[ti + k];
            float ai  = (k == i) ? 0.f : g[si + k];
            float br_ = f[tj + k];
            float bi  = (k == j) ? 0.f : g[sj + k];
            re += ar_ * br_ + ai * bi;
            im += ai * br_ - ar_ * bi;
        }
        unsigned int reb = (unsigned int)f2bf(re);
        unsigned int imb = (unsigned int)f2bf(im);
        unsigned int imn = (unsigned int)f2bf(-im);
        size_t base = brn ? (size_t)PLANE : 0;
        size_t q1 = (size_t)(r0 + r) * 144 + (size_t)(i * 12 + j);
        O32[base + q1] = imb | (reb << 16);
        if (i != j) {
            size_t q2 = (size_t)(r0 + r) * 144 + (size_t)(j * 12 + i);
            O32[base + q2] = imn | (reb << 16);
        }
    }
}

// ---------------------------------------------------------------------------
extern "C" void kernel_launch(void* const* d_in, const int* in_sizes, int n_in,
                              void* d_out, int out_size, void* d_ws, size_t ws_size,
                              hipStream_t stream) {
    const float* X   = (const float*)d_in[0];
    const float* WC1 = (const float*)d_in[1];
    const float* bC1 = (const float*)d_in[2];
    const float* WC2 = (const float*)d_in[3];
    const float* bC2 = (const float*)d_in[4];
    const float* WC3 = (const float*)d_in[5];
    const float* bC3 = (const float*)d_in[6];
    const float* WR1 = (const float*)d_in[7];
    const float* bR1 = (const float*)d_in[8];
    const float* WR2 = (const float*)d_in[9];
    const float* bR2 = (const float*)d_in[10];
    const float* WR3 = (const float*)d_in[11];
    const float* bR3 = (const float*)d_in[12];

    unsigned short* Wt  = (unsigned short*)d_ws;            // 1 MB frag-major
    float* PART = (float*)((char*)d_ws + (2u << 20));       // 32 MB f32 partials
    unsigned int* O32 = (unsigned int*)d_out;

    wt_kernel<<<dim3(64, 2), 256, 0, stream>>>(WC1, WR1, Wt);
    // MEASUREMENT: 5x gemm1 (idempotent). g_warm = (dur13 - dur12)/4.
    for (int rep = 0; rep < 5; ++rep)
        gemm1_kernel<<<64 * KCH, 512, 0, stream>>>(X, Wt, PART);
    tail_kernel<<<M_ROWS / 16, 512, 0, stream>>>(
        PART, bC1, bR1, WC2, bC2, WR2, bR2, WC3, bC3, WR3, bR3, O32);
}

// Round 14
// 258.786 us; speedup vs baseline: 1.5617x; 1.5617x over previous
//
#include <hip/hip_runtime.h>
#include <stdint.h>

// Problem dims (fixed by reference)
#define M_ROWS 8192
#define K_DIM  4096
#define OUTD   144     // per-branch flat size (78 real + 66 imag)
#define PLANE  1179648 // complex elements per output plane (8192*144), u32 units
#define KCH    8       // split-K chunks
#define NSTEP  8       // (K_DIM/KCH)/64 steps of 64k per chunk

typedef __attribute__((ext_vector_type(4))) float  float4v;
typedef __attribute__((ext_vector_type(8))) short  short8v;
typedef __attribute__((ext_vector_type(4))) short  short4v;

static __device__ __forceinline__ unsigned short f2bf(float f) {
    unsigned int u = __builtin_bit_cast(unsigned int, f);
    u += 0x7FFFu + ((u >> 16) & 1u);
    return (unsigned short)(u >> 16);
}
static __device__ __forceinline__ float bf2f(unsigned short h) {
    unsigned int u = ((unsigned int)h) << 16;
    return __builtin_bit_cast(float, u);
}

// ---------------------------------------------------------------------------
// Prep 1: Wt2 frag-major layout for GEMM1 B (unchanged, verified r8-r13).
// ---------------------------------------------------------------------------
__global__ __launch_bounds__(256) void wt_kernel(
    const float* __restrict__ WC1, const float* __restrict__ WR1,
    unsigned short* __restrict__ Wt) {
    __shared__ float tile[64][65];
    const float* src = (blockIdx.y == 0) ? WC1 : WR1;
    const int k0 = blockIdx.x * 64;
    const int t = threadIdx.x;
    const int j = t & 63, qq = t >> 6;
#pragma unroll
    for (int p = 0; p < 16; ++p) {
        int i = p * 4 + qq;
        tile[i][j] = src[(size_t)(k0 + i) * 64 + j];
    }
    __syncthreads();
    const int tt  = blockIdx.x >> 1;
    const int ksb = (blockIdx.x & 1) * 2;
#pragma unroll
    for (int p = 0; p < 16; ++p) {
        int c = p * 256 + t;
        int e = c & 7, m = (c >> 3) & 15, q = (c >> 7) & 3;
        int ks_l = (c >> 9) & 1, w_l = (c >> 10) & 3;
        int kp = ks_l * 32 + q * 8 + e;
        int np = w_l * 16 + m;
        int wg = blockIdx.y * 4 + w_l;
        size_t dst = ((size_t)(wg * 32 + tt) * 4 + (ksb + ks_l)) * 512
                   + q * 128 + m * 8 + e;
        Wt[dst] = f2bf(tile[kp][np]);
    }
}

// ---------------------------------------------------------------------------
// Prep 2 (NEW): W2/W3 as bf16 hi/lo MFMA B-fragments.
// Slots: 0..15 = W2 (br*4+nt)*2+ks ; 16..51 = W3 16+(br*9+nt)*2+ks.
// elem[(slot*2+hl)*512 + q*128 + n*8 + e] = hi/lo of W[k=ks*32+q*8+e][nt*16+n].
// ---------------------------------------------------------------------------
__global__ __launch_bounds__(256) void w23_kernel(
    const float* __restrict__ WC2, const float* __restrict__ WR2,
    const float* __restrict__ WC3, const float* __restrict__ WR3,
    unsigned short* __restrict__ W23f) {
    for (int idx = blockIdx.x * 256 + threadIdx.x; idx < 52 * 512;
         idx += 256 * 8) {
        int slot = idx >> 9, r = idx & 511;
        int qq = r >> 7, n = (r >> 3) & 15, e = r & 7;
        float val;
        if (slot < 16) {
            int br = slot >> 3, nt = (slot >> 1) & 3, ks = slot & 1;
            int k = ks * 32 + qq * 8 + e, col = nt * 16 + n;
            val = (br ? WR2 : WC2)[k * 64 + col];
        } else {
            int g = slot - 16;
            int br = g / 18, t2 = g % 18, nt = t2 >> 1, ks = t2 & 1;
            int k = ks * 32 + qq * 8 + e, col = nt * 16 + n;
            val = (br ? WR3 : WC3)[k * OUTD + col];
        }
        unsigned short hi = f2bf(val);
        unsigned short lo = f2bf(val - bf2f(hi));
        W23f[(size_t)(slot * 2) * 512 + r]     = hi;
        W23f[(size_t)(slot * 2 + 1) * 512 + r] = lo;
    }
}

// ---------------------------------------------------------------------------
// GEMM1: split-K (verbatim r12/r13; measured 33 us warm).
// ---------------------------------------------------------------------------
#define ISSUE_AX(S_, X0_, X1_, X2_, X3_)                       \
    do { const float* ap_ = xpw + (S_) * 64;                   \
         X0_ = *(const float4*)(ap_);                          \
         X1_ = *(const float4*)(ap_ + 4);                      \
         X2_ = *(const float4*)(ap_ + 32);                     \
         X3_ = *(const float4*)(ap_ + 36); } while (0)

#define STORE_AX(BUF_, X0_, X1_, X2_, X3_)                             \
    do { short8v s1_, s2_;                                             \
         s1_[0] = (short)f2bf((X0_).x); s1_[1] = (short)f2bf((X0_).y); \
         s1_[2] = (short)f2bf((X0_).z); s1_[3] = (short)f2bf((X0_).w); \
         s1_[4] = (short)f2bf((X1_).x); s1_[5] = (short)f2bf((X1_).y); \
         s1_[6] = (short)f2bf((X1_).z); s1_[7] = (short)f2bf((X1_).w); \
         s2_[0] = (short)f2bf((X2_).x); s2_[1] = (short)f2bf((X2_).y); \
         s2_[2] = (short)f2bf((X2_).z); s2_[3] = (short)f2bf((X2_).w); \
         s2_[4] = (short)f2bf((X3_).x); s2_[5] = (short)f2bf((X3_).y); \
         s2_[6] = (short)f2bf((X3_).z); s2_[7] = (short)f2bf((X3_).w); \
         *(short8v*)(awp + (BUF_) * 8192) = s1_;                       \
         *(short8v*)(awp + (BUF_) * 8192 + 512) = s2_; } while (0)

#define ISSUE_B2(S_, B0_, B1_)                                   \
    do { const unsigned short* bp_ = bpw + (size_t)(2 * (S_)) * 512; \
         B0_ = *(const short8v*)(bp_);                           \
         B1_ = *(const short8v*)(bp_ + 512); } while (0)

#define MFR2(BUF_, B0_, B1_)                                                   \
    do { _Pragma("unroll")                                                     \
         for (int rb = 0; rb < 8; ++rb) {                                      \
             const unsigned short* ab_ = Asm_ + (BUF_) * 8192 + rb * 1024 + lane * 8; \
             short8v a0_ = *(const short8v*)(ab_);                             \
             short8v a1_ = *(const short8v*)(ab_ + 512);                       \
             acc[rb] = __builtin_amdgcn_mfma_f32_16x16x32_bf16(a0_, B0_, acc[rb], 0, 0, 0); \
             acc[rb] = __builtin_amdgcn_mfma_f32_16x16x32_bf16(a1_, B1_, acc[rb], 0, 0, 0); \
         } } while (0)

__global__ __launch_bounds__(512, 4) void gemm1_kernel(
    const float* __restrict__ X, const unsigned short* __restrict__ Wt,
    float* __restrict__ PART) {
    __shared__ __align__(16) unsigned short Asm_[2 * 8192];

    const int tid  = threadIdx.x;
    const int lane = tid & 63;
    const int w    = tid >> 6;
    const int m    = lane & 15, q = lane >> 4;
    const int mt   = blockIdx.x & 63;
    const int kc   = blockIdx.x >> 6;
    const int r0   = mt * 128;

    const int srow = tid & 127, sq8 = tid >> 7;
    const float* xpw = X + (size_t)(r0 + srow) * K_DIM + kc * 512 + sq8 * 8;
    unsigned short* awp = Asm_ + (srow >> 4) * 1024 + (16 * sq8 + (srow & 15)) * 8;
    const unsigned short* bpw = Wt + (size_t)(w * 128 + kc * 16) * 512 + lane * 8;

    float4v acc[8];
#pragma unroll
    for (int rb = 0; rb < 8; ++rb) acc[rb] = (float4v){0.f, 0.f, 0.f, 0.f};

    float4 xa0, xa1, xa2, xa3;
    short8v bA0, bA1, bB0, bB1;

    ISSUE_AX(0, xa0, xa1, xa2, xa3);
    ISSUE_B2(0, bA0, bA1);

#pragma unroll 1
    for (int sp = 0; sp < NSTEP / 2; ++sp) {
        const int s = sp * 2;
        STORE_AX(0, xa0, xa1, xa2, xa3);
        ISSUE_AX(s + 1, xa0, xa1, xa2, xa3);
        asm volatile("s_waitcnt lgkmcnt(0)" ::: "memory");
        __builtin_amdgcn_s_barrier();
        __builtin_amdgcn_sched_barrier(0);
        ISSUE_B2(s + 1, bB0, bB1);
        MFR2(0, bA0, bA1);
        STORE_AX(1, xa0, xa1, xa2, xa3);
        if (s + 2 < NSTEP) ISSUE_AX(s + 2, xa0, xa1, xa2, xa3);
        asm volatile("s_waitcnt lgkmcnt(0)" ::: "memory");
        __builtin_amdgcn_s_barrier();
        __builtin_amdgcn_sched_barrier(0);
        if (s + 2 < NSTEP) ISSUE_B2(s + 2, bA0, bA1);
        MFR2(1, bB0, bB1);
    }

    {
        float* Pf = PART + (size_t)kc * (M_ROWS * 128);
        const int col = w * 16 + m;
#pragma unroll
        for (int rb = 0; rb < 8; ++rb)
#pragma unroll
            for (int i = 0; i < 4; ++i) {
                int grow = r0 + rb * 16 + q * 4 + i;
                Pf[(size_t)grow * 128 + col] = acc[rb][i];
            }
    }
}

#define MFMA16(A_, B_, C_) __builtin_amdgcn_mfma_f32_16x16x32_bf16(A_, B_, C_, 0, 0, 0)

// ---------------------------------------------------------------------------
// tail v2: reduce -> h1(bf16 hi/lo) -> layer2 MFMA -> layer3 MFMA -> softplus
// -> Cholesky outer product. Layers 2/3 use bf16x3 emulation (AhBh+AlBh+AhBl,
// ~f32 precision). 4 barriers. 16 rows/block, 512 blocks.
// ---------------------------------------------------------------------------
__global__ __launch_bounds__(512, 4) void tail_kernel(
    const float* __restrict__ PART, const unsigned short* __restrict__ W23f,
    const float* __restrict__ bC1, const float* __restrict__ bR1,
    const float* __restrict__ bC2, const float* __restrict__ bR2,
    const float* __restrict__ bC3, const float* __restrict__ bR3,
    unsigned int* __restrict__ O32) {
    // LDS: h1/h2 hi+lo bf16 [16][136] (4 x 4352 B) + fl f32 [16][288] = 35840 B
    __shared__ __align__(16) unsigned short h1h[16 * 136];
    __shared__ __align__(16) unsigned short h1l[16 * 136];
    __shared__ __align__(16) unsigned short h2h[16 * 136];
    __shared__ __align__(16) unsigned short h2l[16 * 136];
    __shared__ __align__(16) float fl[16 * 288];

    const int tid = threadIdx.x, lane = tid & 63, w = tid >> 6;
    const int m = lane & 15, q = lane >> 4;
    const int r0 = blockIdx.x * 16;

    // Prefetch this wave's W2 frags (phase-2 role: br2 = w>>2, nt2 = w&3)
    const int br2 = w >> 2, nt2 = w & 3;
    const int slot2 = (br2 * 4 + nt2) * 2;
    const unsigned short* wf = W23f + lane * 8;
    short8v w2h0 = *(const short8v*)(wf + (size_t)((slot2 + 0) * 2 + 0) * 512);
    short8v w2l0 = *(const short8v*)(wf + (size_t)((slot2 + 0) * 2 + 1) * 512);
    short8v w2h1 = *(const short8v*)(wf + (size_t)((slot2 + 1) * 2 + 0) * 512);
    short8v w2l1 = *(const short8v*)(wf + (size_t)((slot2 + 1) * 2 + 1) * 512);
    const float bv2 = (br2 ? bR2 : bC2)[nt2 * 16 + m];

    // ---- PART reduce -> h1 = relu(sum + b1), split hi/lo bf16 ----
    {
        int r = tid >> 5, c4 = tid & 31;
        const float* p0 = PART + (size_t)(r0 + r) * 128 + c4 * 4;
        float4 s = *(const float4*)p0;
#pragma unroll
        for (int kc = 1; kc < KCH; ++kc) {
            float4 v = *(const float4*)(p0 + (size_t)kc * (M_ROWS * 128));
            s.x += v.x; s.y += v.y; s.z += v.z; s.w += v.w;
        }
        int c = c4 * 4;
        const float* b1 = (c < 64) ? (bC1 + c) : (bR1 + (c - 64));
        float v0 = fmaxf(s.x + b1[0], 0.f);
        float v1 = fmaxf(s.y + b1[1], 0.f);
        float v2 = fmaxf(s.z + b1[2], 0.f);
        float v3 = fmaxf(s.w + b1[3], 0.f);
        short4v hh, hl;
        hh.x = (short)f2bf(v0); hl.x = (short)f2bf(v0 - bf2f((unsigned short)hh.x));
        hh.y = (short)f2bf(v1); hl.y = (short)f2bf(v1 - bf2f((unsigned short)hh.y));
        hh.z = (short)f2bf(v2); hl.z = (short)f2bf(v2 - bf2f((unsigned short)hh.z));
        hh.w = (short)f2bf(v3); hl.w = (short)f2bf(v3 - bf2f((unsigned short)hh.w));
        *(short4v*)&h1h[r * 136 + c] = hh;
        *(short4v*)&h1l[r * 136 + c] = hl;
    }
    __syncthreads();

    // ---- Phase 2: h2 = relu(h1 @ W2 + b2), MFMA bf16x3 ----
    {
        const unsigned short* ah = h1h + m * 136 + br2 * 64 + q * 8;
        const unsigned short* al = h1l + m * 136 + br2 * 64 + q * 8;
        short8v a_h0 = *(const short8v*)(ah);
        short8v a_l0 = *(const short8v*)(al);
        short8v a_h1 = *(const short8v*)(ah + 32);
        short8v a_l1 = *(const short8v*)(al + 32);
        float4v acc = {0.f, 0.f, 0.f, 0.f};
        acc = MFMA16(a_h0, w2h0, acc);
        acc = MFMA16(a_l0, w2h0, acc);
        acc = MFMA16(a_h0, w2l0, acc);
        acc = MFMA16(a_h1, w2h1, acc);
        acc = MFMA16(a_l1, w2h1, acc);
        acc = MFMA16(a_h1, w2l1, acc);
        const int col = br2 * 64 + nt2 * 16 + m;
#pragma unroll
        for (int i = 0; i < 4; ++i) {
            float v = fmaxf(acc[i] + bv2, 0.f);
            unsigned short hi = f2bf(v);
            h2h[(q * 4 + i) * 136 + col] = hi;
            h2l[(q * 4 + i) * 136 + col] = f2bf(v - bf2f(hi));
        }
    }
    __syncthreads();

    // ---- Phase 3: fl = h2 @ W3 + b3, MFMA bf16x3 ----
#pragma unroll 1
    for (int pair = w; pair < 18; pair += 8) {
        const int br = (pair >= 9) ? 1 : 0;
        const int nt = pair - br * 9;
        const int slot3 = 16 + (br * 9 + nt) * 2;
        short8v b_h0 = *(const short8v*)(wf + (size_t)((slot3 + 0) * 2 + 0) * 512);
        short8v b_l0 = *(const short8v*)(wf + (size_t)((slot3 + 0) * 2 + 1) * 512);
        short8v b_h1 = *(const short8v*)(wf + (size_t)((slot3 + 1) * 2 + 0) * 512);
        short8v b_l1 = *(const short8v*)(wf + (size_t)((slot3 + 1) * 2 + 1) * 512);
        const unsigned short* ah = h2h + m * 136 + br * 64 + q * 8;
        const unsigned short* al = h2l + m * 136 + br * 64 + q * 8;
        short8v a_h0 = *(const short8v*)(ah);
        short8v a_l0 = *(const short8v*)(al);
        short8v a_h1 = *(const short8v*)(ah + 32);
        short8v a_l1 = *(const short8v*)(al + 32);
        float4v acc = {0.f, 0.f, 0.f, 0.f};
        acc = MFMA16(a_h0, b_h0, acc);
        acc = MFMA16(a_l0, b_h0, acc);
        acc = MFMA16(a_h0, b_l0, acc);
        acc = MFMA16(a_h1, b_h1, acc);
        acc = MFMA16(a_l1, b_h1, acc);
        acc = MFMA16(a_h1, b_l1, acc);
        const float bv3 = (br ? bR3 : bC3)[nt * 16 + m];
#pragma unroll
        for (int i = 0; i < 4; ++i)
            fl[(q * 4 + i) * 288 + br * 144 + nt * 16 + m] = acc[i] + bv3;
    }
    __syncthreads();

    // ---- Phase 4: softplus on the 12 diag reals per (row,brn) ----
    if (tid < 384) {
        int r = tid / 24, rem = tid % 24;
        int brn = rem / 12, ii = rem % 12;
        float* f = &fl[r * 288 + brn * 144];
        int d = ii * (ii + 1) / 2 + ii;
        float xv = f[d];
        f[d] = (xv > 20.f) ? xv : log1pf(expf(xv));
    }
    __syncthreads();

    // ---- Phase 5: C = L L^H, Hermitian mirror, write OUT ----
    for (int task = tid; task < 16 * 2 * 78; task += 512) {
        int r = task / 156, rem = task % 156;
        int brn = rem / 78, p = rem % 78;
        int i = 0;
        while (p >= (i + 1) * (i + 2) / 2) ++i;
        int j = p - i * (i + 1) / 2;              // j <= i
        const float* f = &fl[r * 288 + brn * 144];
        const float* g = f + 78;
        const int ti = i * (i + 1) / 2, tj = j * (j + 1) / 2;
        const int si = i * (i - 1) / 2, sj = j * (j - 1) / 2;
        float re = 0.f, im = 0.f;
        for (int k = 0; k <= j; ++k) {
            float ar_ = f[ti + k];
            float ai  = (k == i) ? 0.f : g[si + k];
            float br_ = f[tj + k];
            float bi  = (k == j) ? 0.f : g[sj + k];
            re += ar_ * br_ + ai * bi;
            im += ai * br_ - ar_ * bi;
        }
        unsigned int reb = (unsigned int)f2bf(re);
        unsigned int imb = (unsigned int)f2bf(im);
        unsigned int imn = (unsigned int)f2bf(-im);
        size_t base = brn ? (size_t)PLANE : 0;
        size_t q1 = (size_t)(r0 + r) * 144 + (size_t)(i * 12 + j);
        O32[base + q1] = imb | (reb << 16);
        if (i != j) {
            size_t q2 = (size_t)(r0 + r) * 144 + (size_t)(j * 12 + i);
            O32[base + q2] = imn | (reb << 16);
        }
    }
}

// ---------------------------------------------------------------------------
extern "C" void kernel_launch(void* const* d_in, const int* in_sizes, int n_in,
                              void* d_out, int out_size, void* d_ws, size_t ws_size,
                              hipStream_t stream) {
    const float* X   = (const float*)d_in[0];
    const float* WC1 = (const float*)d_in[1];
    const float* bC1 = (const float*)d_in[2];
    const float* WC2 = (const float*)d_in[3];
    const float* bC2 = (const float*)d_in[4];
    const float* WC3 = (const float*)d_in[5];
    const float* bC3 = (const float*)d_in[6];
    const float* WR1 = (const float*)d_in[7];
    const float* bR1 = (const float*)d_in[8];
    const float* WR2 = (const float*)d_in[9];
    const float* bR2 = (const float*)d_in[10];
    const float* WR3 = (const float*)d_in[11];
    const float* bR3 = (const float*)d_in[12];

    unsigned short* Wt   = (unsigned short*)d_ws;             // 1 MB @ 0
    unsigned short* W23f = (unsigned short*)((char*)d_ws + (1u << 20)); // 104 KB @ 1MB
    float* PART = (float*)((char*)d_ws + (2u << 20));         // 32 MB @ 2MB
    unsigned int* O32 = (unsigned int*)d_out;

    wt_kernel<<<dim3(64, 2), 256, 0, stream>>>(WC1, WR1, Wt);
    w23_kernel<<<8, 256, 0, stream>>>(WC2, WR2, WC3, WR3, W23f);
    gemm1_kernel<<<64 * KCH, 512, 0, stream>>>(X, Wt, PART);
    tail_kernel<<<M_ROWS / 16, 512, 0, stream>>>(
        PART, W23f, bC1, bR1, bC2, bR2, bC3, bR3, O32);
}